// Round 8
// baseline (450.523 us; speedup 1.0000x reference)
//
#include <hip/hip_runtime.h>

// CAttention on MI355X (gfx950). Inputs f32, output f32.
// Q = box3(x)*log2(e), K = V = normalize(x+EPS), softmax over keys, per batch.
// Round 8: round 7 structure with the prep kT overrun fixed (c<128 single pass).
// S^T trick (P born near-A-layout), QK frags from L2 (no sK), S=8 split-K with
// fused last-block combine (atomic counter), single fused prep kernel.
// ws: kmat bf16 @0 | kT bf16 @4M | xbT bf16 @8M | lsum f32 @12M | counters @12M+512K | opart bf16 @13M.

typedef short bf16x8 __attribute__((ext_vector_type(8)));
typedef float f32x4 __attribute__((ext_vector_type(4)));
typedef unsigned short u16x4 __attribute__((ext_vector_type(4)));
typedef unsigned int u32x2 __attribute__((ext_vector_type(2)));

#define L2E 1.4426950408889634f

__device__ __forceinline__ unsigned short f2bf(float f) {
    unsigned int u;
    __builtin_memcpy(&u, &f, 4);
    u = u + 0x7FFFu + ((u >> 16) & 1u);   // RNE
    return (unsigned short)(u >> 16);
}
__device__ __forceinline__ float bf2f(unsigned short h) {
    unsigned int u = ((unsigned int)h) << 16;
    float f;
    __builtin_memcpy(&f, &u, 4);
    return f;
}
// pack two f32 -> bf16 pair (round to nearest, ties up)
__device__ __forceinline__ unsigned int pk_bf16(float a, float b) {
    unsigned int ua, ub;
    __builtin_memcpy(&ua, &a, 4);
    __builtin_memcpy(&ub, &b, 4);
    return ((ua + 0x8000u) >> 16) | ((ub + 0x8000u) & 0xFFFF0000u);
}

// ---------------- K1: fused prep: kmat, kT, xbT (+ counter zero) -------------------------
// grid (64 p, 2 qhalf, 4 b) x 256. Block: 32 pixels (row p, cols q0..q0+31), all 128 c.
__global__ void prep(const float* __restrict__ x,
                     unsigned short* __restrict__ kmat,
                     unsigned short* __restrict__ kT,
                     unsigned short* __restrict__ xbT,
                     unsigned int* __restrict__ counters) {
    const int p = blockIdx.x, qh = blockIdx.y, b = blockIdx.z, t = threadIdx.x;
    const int q0 = qh * 32;
    if (qh == 0 && t == 0) counters[b * 32 + (p >> 1)] = 0;

    __shared__ float sX[8][3][36];
    __shared__ float sMidT[32 * 132];     // [q][c], stride 132 (16B-mult)
    __shared__ __align__(16) unsigned short sQ[32 * 136];
    __shared__ float sqp[256];
    __shared__ float sInv[32];

    const int ccOwn = t >> 5, qOwn = t & 31;
    float sqacc = 0.f;

    for (int c0 = 0; c0 < 128; c0 += 8) {
        __syncthreads();
#pragma unroll
        for (int i = 0; i < 4; i++) {
            int j = i * 256 + t;
            if (j < 816) {                       // 8cc x 3r x 34q
                int cc = j / 102, rem = j - cc * 102;
                int r = rem / 34, qq = rem - r * 34;
                int pp = p + r - 1, qg = q0 + qq - 1;
                float v = 0.f;
                if ((unsigned)pp < 64u && (unsigned)qg < 64u)
                    v = x[((size_t)b * 128 + c0 + cc) * 4096 + pp * 64 + qg];
                sX[cc][r][qq] = v;
            }
        }
        __syncthreads();
        float mid = sX[ccOwn][1][qOwn + 1] + 1e-7f;
        sMidT[qOwn * 132 + c0 + ccOwn] = mid;
        sqacc += mid * mid;
        float sbox = 0.f;
#pragma unroll
        for (int r = 0; r < 3; r++)
            sbox += sX[ccOwn][r][qOwn] + sX[ccOwn][r][qOwn + 1] + sX[ccOwn][r][qOwn + 2];
        sQ[qOwn * 136 + c0 + ccOwn] = f2bf(sbox * L2E);
    }
    sqp[ccOwn * 32 + qOwn] = sqacc;
    __syncthreads();
    if (t < 32) {
        float ss = 0.f;
#pragma unroll
        for (int g = 0; g < 8; g++) ss += sqp[g * 32 + t];
        sInv[t] = rsqrtf(ss);
    }
    __syncthreads();

    // xbT rows (32 x 128), 16B coalesced
#pragma unroll
    for (int i = 0; i < 2; i++) {
        int e = (i * 256 + t) * 8, row = e >> 7, col = e & 127;
        *(bf16x8*)(xbT + ((size_t)b * 4096 + p * 64 + q0 + row) * 128 + col) =
            *(const bf16x8*)(sQ + row * 136 + col);
    }
    // kmat rows: k = mid * inv  (512 items = 32q x 16 col-groups)
#pragma unroll
    for (int i = 0; i < 2; i++) {
        int u = i * 256 + t, q = u >> 4, cg = u & 15;
        float iv = sInv[q];
        f32x4 a = *(const f32x4*)(sMidT + q * 132 + cg * 8);
        f32x4 c = *(const f32x4*)(sMidT + q * 132 + cg * 8 + 4);
        unsigned int w[4];
        w[0] = pk_bf16(a[0] * iv, a[1] * iv);
        w[1] = pk_bf16(a[2] * iv, a[3] * iv);
        w[2] = pk_bf16(c[0] * iv, c[1] * iv);
        w[3] = pk_bf16(c[2] * iv, c[3] * iv);
        *(uint4*)(kmat + ((size_t)b * 4096 + p * 64 + q0 + q) * 128 + cg * 8) =
            make_uint4(w[0], w[1], w[2], w[3]);
    }
    // kT rows [c][l]: exactly 256 items = 128c x 2 halves (ROUND-8 FIX: was 512 -> overran)
    {
        int c = t >> 1, half = t & 1;
        unsigned int w[8];
#pragma unroll
        for (int j = 0; j < 8; j++) {
            int ql = half * 16 + j * 2;
            w[j] = pk_bf16(sMidT[ql * 132 + c] * sInv[ql],
                           sMidT[(ql + 1) * 132 + c] * sInv[ql + 1]);
        }
        unsigned short* dst = kT + ((size_t)b * 128 + c) * 4096 + p * 64 + q0 + half * 16;
        *(uint4*)(dst) = make_uint4(w[0], w[1], w[2], w[3]);
        *(uint4*)(dst + 8) = make_uint4(w[4], w[5], w[6], w[7]);
    }
}

// ---------------- K2: split-K flash + fused combine --------------------------------------
#define SV_STRIDE 72

__global__ void __launch_bounds__(256, 3) flash_attn(
        const unsigned short* __restrict__ kmat,
        const unsigned short* __restrict__ kT,
        const unsigned short* __restrict__ xbT,
        const float* __restrict__ x,
        const float* __restrict__ mask,
        unsigned short* __restrict__ opart,
        float* __restrict__ lsum,
        float* __restrict__ out,
        unsigned int* __restrict__ counters,
        int nsplit, int qbshift) {
    const int combo = blockIdx.x & (4 * nsplit - 1);
    const int qb = blockIdx.x >> qbshift;        // 128-query tile, 0..31
    const int b = combo & 3, split = combo >> 2;
    const int nk = 4096 / nsplit, NIT = nk >> 6, kt_base = split * nk;
    const int t = threadIdx.x;
    const int wave = t >> 6, lane = t & 63;
    const int l16 = lane & 15, quad = lane >> 4;

    __shared__ __align__(16) unsigned short smem[18432];   // 36864 B (sV+sP / sO union)
    unsigned short* sV = smem;                              // [128 ch][72]
    unsigned short* sP = smem + 9216 + wave * 2304;         // per-wave [32 q][72]
    __shared__ float Linv[128];
    __shared__ int isLast;

    // Q frags (B-operand of S^T): B[n=q=l16][k=c=quad*8+j]
    bf16x8 aq[2][4];
#pragma unroll
    for (int h = 0; h < 2; h++) {
        const unsigned short* xq =
            xbT + ((size_t)b * 4096 + qb * 128 + wave * 32 + h * 16 + l16) * 128 + quad * 8;
#pragma unroll
        for (int cc = 0; cc < 4; cc++) aq[h][cc] = *(const bf16x8*)(xq + cc * 32);
    }

    f32x4 o[2][8];
#pragma unroll
    for (int h = 0; h < 2; h++)
#pragma unroll
        for (int n = 0; n < 8; n++) o[h][n] = (f32x4){0.f, 0.f, 0.f, 0.f};
    float rs[2] = {0.f, 0.f};

    const unsigned short* kmb = kmat + (size_t)b * 4096 * 128;
    const unsigned short* ktb = kT + (size_t)b * 128 * 4096;
    // per-lane QK A-frag base: row kt_base + l16, col quad*8
    const unsigned short* kf = kmb + (size_t)(kt_base + l16) * 128 + quad * 8;

    bf16x8 vreg[4];
#pragma unroll
    for (int i = 0; i < 4; i++) {
        int e = i * 2048 + t * 8;
        vreg[i] = *(const bf16x8*)(ktb + (size_t)(e >> 6) * 4096 + kt_base + (e & 63));
    }

    for (int it = 0; it < NIT; it++) {
        __syncthreads();
#pragma unroll
        for (int i = 0; i < 4; i++) {
            int e = i * 2048 + t * 8;
            *(bf16x8*)(sV + (e >> 6) * SV_STRIDE + (e & 63)) = vreg[i];
        }
        __syncthreads();
        if (it + 1 < NIT) {
            int kt0 = kt_base + (it + 1) * 64;
#pragma unroll
            for (int i = 0; i < 4; i++) {
                int e = i * 2048 + t * 8;
                vreg[i] = *(const bf16x8*)(ktb + (size_t)(e >> 6) * 4096 + kt0 + (e & 63));
            }
        }

        // S^T = K Q^T: A = kmat frags straight from global (L2-hot via XCD swizzle).
        // D layout: lane holds S^T[key = k4*16 + quad*4 + r][q = l16].
        f32x4 s[2][4];
#pragma unroll
        for (int h = 0; h < 2; h++)
#pragma unroll
            for (int k4 = 0; k4 < 4; k4++) s[h][k4] = (f32x4){0.f, 0.f, 0.f, 0.f};
        const unsigned short* kfi = kf + (size_t)it * 64 * 128;
#pragma unroll
        for (int cc = 0; cc < 4; cc++) {
#pragma unroll
            for (int k4 = 0; k4 < 4; k4++) {
                bf16x8 kfr = *(const bf16x8*)(kfi + k4 * 2048 + cc * 32);
                s[0][k4] = __builtin_amdgcn_mfma_f32_16x16x32_bf16(kfr, aq[0][cc], s[0][k4], 0, 0, 0);
                s[1][k4] = __builtin_amdgcn_mfma_f32_16x16x32_bf16(kfr, aq[1][cc], s[1][k4], 0, 0, 0);
            }
        }

        // p = 2^s; lane-local row sum (q = l16 fixed); pack consecutive-key pairs -> sP
#pragma unroll
        for (int h = 0; h < 2; h++) {
#pragma unroll
            for (int k4 = 0; k4 < 4; k4++) {
                float p0 = exp2f(s[h][k4][0]), p1 = exp2f(s[h][k4][1]);
                float p2 = exp2f(s[h][k4][2]), p3 = exp2f(s[h][k4][3]);
                rs[h] += (p0 + p1) + (p2 + p3);
                u32x2 d;
                d[0] = pk_bf16(p0, p1);
                d[1] = pk_bf16(p2, p3);
                // P[q=l16][key = k4*16 + quad*4 + 0..3]
                *(u32x2*)(sP + (h * 16 + l16) * 72 + k4 * 16 + quad * 4) = d;
            }
        }
        asm volatile("" ::: "memory");   // DS in-order per wave; stop compiler reorder
        bf16x8 pa[2][2];
#pragma unroll
        for (int h = 0; h < 2; h++)
#pragma unroll
            for (int kc = 0; kc < 2; kc++)
                pa[h][kc] = *(const bf16x8*)(sP + (h * 16 + l16) * 72 + kc * 32 + quad * 8);
        asm volatile("" ::: "memory");

        // O += P V
#pragma unroll
        for (int kc = 0; kc < 2; kc++)
#pragma unroll
            for (int n = 0; n < 8; n++) {
                bf16x8 bv = *(const bf16x8*)(sV + (n * 16 + l16) * SV_STRIDE + kc * 32 + quad * 8);
                o[0][n] = __builtin_amdgcn_mfma_f32_16x16x32_bf16(pa[0][kc], bv, o[0][n], 0, 0, 0);
                o[1][n] = __builtin_amdgcn_mfma_f32_16x16x32_bf16(pa[1][kc], bv, o[1][n], 0, 0, 0);
            }
    }

    // row-sums: reduce across quads (keys were quad-distributed)
#pragma unroll
    for (int h = 0; h < 2; h++) {
        rs[h] += __shfl_xor(rs[h], 16);
        rs[h] += __shfl_xor(rs[h], 32);
    }
    if (lane < 16) {
#pragma unroll
        for (int h = 0; h < 2; h++)
            lsum[(size_t)(split * 4 + b) * 4096 + qb * 128 + wave * 32 + h * 16 + lane] = rs[h];
    }

    // O partial -> bf16 opart via LDS transpose, two 64-q passes
    float* sO = reinterpret_cast<float*>(smem);   // [128 ch][68] f32 = 34816 B
#pragma unroll
    for (int half = 0; half < 2; half++) {
        __syncthreads();
        if ((wave >> 1) == half) {
#pragma unroll
            for (int h = 0; h < 2; h++)
#pragma unroll
                for (int n = 0; n < 8; n++)
#pragma unroll
                    for (int r = 0; r < 4; r++)
                        sO[(n * 16 + l16) * 68 + (wave & 1) * 32 + h * 16 + quad * 4 + r] =
                            o[h][n][r];
        }
        __syncthreads();
#pragma unroll
        for (int i = 0; i < 4; i++) {
            int u = i * 256 + t, c = u >> 3, g = u & 7;    // 128c x 8 groups of 8q
            f32x4 v0 = *(const f32x4*)(sO + c * 68 + g * 8);
            f32x4 v1 = *(const f32x4*)(sO + c * 68 + g * 8 + 4);
            unsigned int w[4];
            w[0] = pk_bf16(v0[0], v0[1]);
            w[1] = pk_bf16(v0[2], v0[3]);
            w[2] = pk_bf16(v1[0], v1[1]);
            w[3] = pk_bf16(v1[2], v1[3]);
            *(uint4*)(opart + ((size_t)(split * 4 + b) * 128 + c) * 4096 +
                      qb * 128 + half * 64 + g * 8) = make_uint4(w[0], w[1], w[2], w[3]);
        }
    }

    // last block per (b, qb) combines all splits + mask blend
    __threadfence();
    if (t == 0)
        isLast = (atomicAdd(&counters[b * 32 + qb], 1u) == (unsigned)(nsplit - 1));
    __syncthreads();
    if (!isLast) return;
    __threadfence();
    if (t < 128) {
        float L = 0.f;
        for (int s2 = 0; s2 < nsplit; s2++)
            L += lsum[(size_t)(s2 * 4 + b) * 4096 + qb * 128 + t];
        Linv[t] = 1.f / fmaxf(L, 1e-37f);
    }
    __syncthreads();
#pragma unroll 4
    for (int i = 0; i < 16; i++) {
        int u = i * 256 + t, c = u >> 5, qg = u & 31, q0 = qg * 4;
        f32x4 acc = (f32x4){0.f, 0.f, 0.f, 0.f};
        for (int s2 = 0; s2 < nsplit; s2++) {
            u16x4 pv = *(const u16x4*)(opart + ((size_t)(s2 * 4 + b) * 128 + c) * 4096 +
                                       qb * 128 + q0);
#pragma unroll
            for (int j = 0; j < 4; j++) acc[j] += bf2f(pv[j]);
        }
        f32x4 xv = *(const f32x4*)(x + ((size_t)b * 128 + c) * 4096 + qb * 128 + q0);
        f32x4 mv = *(const f32x4*)(mask + (size_t)b * 4096 + qb * 128 + q0);
        f32x4 res;
#pragma unroll
        for (int j = 0; j < 4; j++)
            res[j] = acc[j] * Linv[q0 + j] * (1.f - mv[j]) * (1.f / 9.f) + xv[j] * mv[j];
        *(f32x4*)(out + ((size_t)b * 128 + c) * 4096 + qb * 128 + q0) = res;
    }
}

extern "C" void kernel_launch(void* const* d_in, const int* in_sizes, int n_in,
                              void* d_out, int out_size, void* d_ws, size_t ws_size,
                              hipStream_t stream) {
    const float* x = (const float*)d_in[0];     // f32 (4,128,64,64)
    const float* mask = (const float*)d_in[1];  // f32 (4,1,64,64)
    float* out = (float*)d_out;                 // f32 (4,128,64,64)
    char* ws = (char*)d_ws;
    unsigned short* kmat = (unsigned short*)(ws);
    unsigned short* kT   = (unsigned short*)(ws + (size_t)4 * 1024 * 1024);
    unsigned short* xbT  = (unsigned short*)(ws + (size_t)8 * 1024 * 1024);
    float* lsum          = (float*)(ws + (size_t)12 * 1024 * 1024);
    unsigned int* counters = (unsigned int*)(ws + (size_t)12 * 1024 * 1024 + 512 * 1024);
    unsigned short* opart  = (unsigned short*)(ws + (size_t)13 * 1024 * 1024);

    // ws need: 13 MiB + S*4 MiB (opart bf16)
    int S, qbshift;
    if (ws_size >= (size_t)45 * 1024 * 1024)      { S = 8; qbshift = 5; }
    else if (ws_size >= (size_t)29 * 1024 * 1024) { S = 4; qbshift = 4; }
    else if (ws_size >= (size_t)21 * 1024 * 1024) { S = 2; qbshift = 3; }
    else return;

    prep<<<dim3(64, 2, 4), 256, 0, stream>>>(x, kmat, kT, xbT, counters);
    flash_attn<<<dim3(32 * 4 * S), 256, 0, stream>>>(kmat, kT, xbT, x, mask,
                                                     opart, lsum, out, counters, S, qbshift);
}

// Round 9
// 286.100 us; speedup vs baseline: 1.5747x; 1.5747x over previous
//
#include <hip/hip_runtime.h>

// CAttention on MI355X (gfx950). Inputs f32, output f32.
// Q = box3(x)*log2(e), K = V = normalize(x+EPS), softmax over keys, per batch.
// Round 9: revert fused combine (threadfence = cross-XCD L2 writeback storm, R8: 162MB
// writes, 560 GB/s, 390us). Separate combine kernel, no fences/atomics. Keep S^T trick,
// QK frags from L2 (no sK), S=8 split-K, bf16 opart. Prep loads now row-coalesced.
// ws: kmat bf16 @0 | kT bf16 @4M | xbT bf16 @8M | lsum f32 @12M | opart bf16 @13M.

typedef short bf16x8 __attribute__((ext_vector_type(8)));
typedef float f32x4 __attribute__((ext_vector_type(4)));
typedef unsigned short u16x4 __attribute__((ext_vector_type(4)));
typedef unsigned int u32x2 __attribute__((ext_vector_type(2)));

#define L2E 1.4426950408889634f

__device__ __forceinline__ unsigned short f2bf(float f) {
    unsigned int u;
    __builtin_memcpy(&u, &f, 4);
    u = u + 0x7FFFu + ((u >> 16) & 1u);   // RNE
    return (unsigned short)(u >> 16);
}
__device__ __forceinline__ float bf2f(unsigned short h) {
    unsigned int u = ((unsigned int)h) << 16;
    float f;
    __builtin_memcpy(&f, &u, 4);
    return f;
}
// pack two f32 -> bf16 pair (round to nearest, ties up)
__device__ __forceinline__ unsigned int pk_bf16(float a, float b) {
    unsigned int ua, ub;
    __builtin_memcpy(&ua, &a, 4);
    __builtin_memcpy(&ub, &b, 4);
    return ((ua + 0x8000u) >> 16) | ((ub + 0x8000u) & 0xFFFF0000u);
}

// ---------------- K1: fused prep: kmat, kT, xbT ------------------------------------------
// grid (64 p, 4 b) x 256. Block: one p-row (64 q) across all 128 c.
// All x loads are full-row 256B wave-coalesced.
__global__ void prep(const float* __restrict__ x,
                     unsigned short* __restrict__ kmat,
                     unsigned short* __restrict__ kT,
                     unsigned short* __restrict__ xbT) {
    const int p = blockIdx.x, b = blockIdx.y, t = threadIdx.x;
    const int wave = t >> 6, lane = t & 63;

    __shared__ float sX[8][3][66];
    __shared__ float sMidT[64 * 132];     // [q][c], stride 132 (16B-mult)
    __shared__ __align__(16) unsigned short sQ[64 * 136];
    __shared__ float sqp[256];
    __shared__ float sInv[64];

    const int ccO = t >> 6;               // wave owns cc pair {ccO*2, ccO*2+1}
    const int qOwn = t & 63;
    float sqacc = 0.f;

    for (int c0 = 0; c0 < 128; c0 += 8) {
        __syncthreads();
        // 24 coalesced row loads: pair = wave*6 + i -> (cc = pair/3, r = pair%3)
#pragma unroll
        for (int i = 0; i < 6; i++) {
            int pair = wave * 6 + i;
            int cc = pair / 3, r = pair - cc * 3;
            int pp = p + r - 1;
            float v = 0.f;
            if ((unsigned)pp < 64u)
                v = x[((size_t)b * 128 + c0 + cc) * 4096 + pp * 64 + lane];
            sX[cc][r][1 + lane] = v;
        }
        if (t < 48) {                     // zero left/right borders: 8cc x 3r x 2side
            int cc = t / 6, rr = (t % 6) >> 1, side = t & 1;
            sX[cc][rr][side * 65] = 0.f;
        }
        __syncthreads();
#pragma unroll
        for (int j = 0; j < 2; j++) {
            int cc = ccO * 2 + j;
            float mid = sX[cc][1][1 + qOwn] + 1e-7f;
            sMidT[qOwn * 132 + c0 + cc] = mid;
            sqacc += mid * mid;
            float sbox = 0.f;
#pragma unroll
            for (int r = 0; r < 3; r++)
                sbox += sX[cc][r][qOwn] + sX[cc][r][qOwn + 1] + sX[cc][r][qOwn + 2];
            sQ[qOwn * 136 + c0 + cc] = f2bf(sbox * L2E);
        }
    }
    sqp[ccO * 64 + qOwn] = sqacc;
    __syncthreads();
    if (t < 64) {
        float ss = sqp[t] + sqp[64 + t] + sqp[128 + t] + sqp[192 + t];
        sInv[t] = rsqrtf(ss);
    }
    __syncthreads();

    // xbT rows (64 x 128), 16B coalesced
#pragma unroll
    for (int i = 0; i < 4; i++) {
        int e = (i * 256 + t) * 8, row = e >> 7, col = e & 127;
        *(bf16x8*)(xbT + ((size_t)b * 4096 + p * 64 + row) * 128 + col) =
            *(const bf16x8*)(sQ + row * 136 + col);
    }
    // kmat rows: k = mid * inv (1024 items = 64q x 16 col-groups)
#pragma unroll
    for (int i = 0; i < 4; i++) {
        int u = i * 256 + t, q = u >> 4, cg = u & 15;
        float iv = sInv[q];
        f32x4 a = *(const f32x4*)(sMidT + q * 132 + cg * 8);
        f32x4 c = *(const f32x4*)(sMidT + q * 132 + cg * 8 + 4);
        unsigned int w[4];
        w[0] = pk_bf16(a[0] * iv, a[1] * iv);
        w[1] = pk_bf16(a[2] * iv, a[3] * iv);
        w[2] = pk_bf16(c[0] * iv, c[1] * iv);
        w[3] = pk_bf16(c[2] * iv, c[3] * iv);
        *(uint4*)(kmat + ((size_t)b * 4096 + p * 64 + q) * 128 + cg * 8) =
            make_uint4(w[0], w[1], w[2], w[3]);
    }
    // kT rows [c][l]: 256 items = 128c x 2 halves of 32 q
    {
        int c = t >> 1, half = t & 1;
        unsigned int w[16];
#pragma unroll
        for (int j = 0; j < 16; j++) {
            int ql = half * 32 + j * 2;
            w[j] = pk_bf16(sMidT[ql * 132 + c] * sInv[ql],
                           sMidT[(ql + 1) * 132 + c] * sInv[ql + 1]);
        }
        unsigned short* dst = kT + ((size_t)b * 128 + c) * 4096 + p * 64 + half * 32;
#pragma unroll
        for (int j = 0; j < 4; j++)
            *(uint4*)(dst + j * 8) = make_uint4(w[4 * j], w[4 * j + 1], w[4 * j + 2], w[4 * j + 3]);
    }
}

// ---------------- K2: split-K flash (S^T trick, no fences) -------------------------------
#define SV_STRIDE 72

__global__ void __launch_bounds__(256, 3) flash_attn(
        const unsigned short* __restrict__ kmat,
        const unsigned short* __restrict__ kT,
        const unsigned short* __restrict__ xbT,
        unsigned short* __restrict__ opart,
        float* __restrict__ lsum,
        int nsplit, int qbshift) {
    const int combo = blockIdx.x & (4 * nsplit - 1);
    const int qb = blockIdx.x >> qbshift;        // 128-query tile, 0..31
    const int b = combo & 3, split = combo >> 2;
    const int nk = 4096 / nsplit, NIT = nk >> 6, kt_base = split * nk;
    const int t = threadIdx.x;
    const int wave = t >> 6, lane = t & 63;
    const int l16 = lane & 15, quad = lane >> 4;

    __shared__ __align__(16) unsigned short smem[18432];   // 36864 B (sV+sP / sO union)
    unsigned short* sV = smem;                              // [128 ch][72]
    unsigned short* sP = smem + 9216 + wave * 2304;         // per-wave [32 q][72]

    // Q frags (B-operand of S^T): B[n=q=l16][k=c=quad*8+j]
    bf16x8 aq[2][4];
#pragma unroll
    for (int h = 0; h < 2; h++) {
        const unsigned short* xq =
            xbT + ((size_t)b * 4096 + qb * 128 + wave * 32 + h * 16 + l16) * 128 + quad * 8;
#pragma unroll
        for (int cc = 0; cc < 4; cc++) aq[h][cc] = *(const bf16x8*)(xq + cc * 32);
    }

    f32x4 o[2][8];
#pragma unroll
    for (int h = 0; h < 2; h++)
#pragma unroll
        for (int n = 0; n < 8; n++) o[h][n] = (f32x4){0.f, 0.f, 0.f, 0.f};
    float rs[2] = {0.f, 0.f};

    const unsigned short* kmb = kmat + (size_t)b * 4096 * 128;
    const unsigned short* ktb = kT + (size_t)b * 128 * 4096;
    const unsigned short* kf = kmb + (size_t)(kt_base + l16) * 128 + quad * 8;

    bf16x8 vreg[4];
#pragma unroll
    for (int i = 0; i < 4; i++) {
        int e = i * 2048 + t * 8;
        vreg[i] = *(const bf16x8*)(ktb + (size_t)(e >> 6) * 4096 + kt_base + (e & 63));
    }

    for (int it = 0; it < NIT; it++) {
        __syncthreads();
#pragma unroll
        for (int i = 0; i < 4; i++) {
            int e = i * 2048 + t * 8;
            *(bf16x8*)(sV + (e >> 6) * SV_STRIDE + (e & 63)) = vreg[i];
        }
        __syncthreads();
        if (it + 1 < NIT) {
            int kt0 = kt_base + (it + 1) * 64;
#pragma unroll
            for (int i = 0; i < 4; i++) {
                int e = i * 2048 + t * 8;
                vreg[i] = *(const bf16x8*)(ktb + (size_t)(e >> 6) * 4096 + kt0 + (e & 63));
            }
        }

        // S^T = K Q^T: A = kmat frags straight from global (L2-hot via XCD swizzle).
        // D layout: lane holds S^T[key = k4*16 + quad*4 + r][q = l16].
        f32x4 s[2][4];
#pragma unroll
        for (int h = 0; h < 2; h++)
#pragma unroll
            for (int k4 = 0; k4 < 4; k4++) s[h][k4] = (f32x4){0.f, 0.f, 0.f, 0.f};
        const unsigned short* kfi = kf + (size_t)it * 64 * 128;
#pragma unroll
        for (int cc = 0; cc < 4; cc++) {
#pragma unroll
            for (int k4 = 0; k4 < 4; k4++) {
                bf16x8 kfr = *(const bf16x8*)(kfi + k4 * 2048 + cc * 32);
                s[0][k4] = __builtin_amdgcn_mfma_f32_16x16x32_bf16(kfr, aq[0][cc], s[0][k4], 0, 0, 0);
                s[1][k4] = __builtin_amdgcn_mfma_f32_16x16x32_bf16(kfr, aq[1][cc], s[1][k4], 0, 0, 0);
            }
        }

        // p = 2^s; lane-local row sum (q = l16 fixed); pack consecutive-key pairs -> sP
#pragma unroll
        for (int h = 0; h < 2; h++) {
#pragma unroll
            for (int k4 = 0; k4 < 4; k4++) {
                float p0 = exp2f(s[h][k4][0]), p1 = exp2f(s[h][k4][1]);
                float p2 = exp2f(s[h][k4][2]), p3 = exp2f(s[h][k4][3]);
                rs[h] += (p0 + p1) + (p2 + p3);
                u32x2 d;
                d[0] = pk_bf16(p0, p1);
                d[1] = pk_bf16(p2, p3);
                *(u32x2*)(sP + (h * 16 + l16) * 72 + k4 * 16 + quad * 4) = d;
            }
        }
        asm volatile("" ::: "memory");   // DS in-order per wave; stop compiler reorder
        bf16x8 pa[2][2];
#pragma unroll
        for (int h = 0; h < 2; h++)
#pragma unroll
            for (int kc = 0; kc < 2; kc++)
                pa[h][kc] = *(const bf16x8*)(sP + (h * 16 + l16) * 72 + kc * 32 + quad * 8);
        asm volatile("" ::: "memory");

        // O += P V
#pragma unroll
        for (int kc = 0; kc < 2; kc++)
#pragma unroll
            for (int n = 0; n < 8; n++) {
                bf16x8 bv = *(const bf16x8*)(sV + (n * 16 + l16) * SV_STRIDE + kc * 32 + quad * 8);
                o[0][n] = __builtin_amdgcn_mfma_f32_16x16x32_bf16(pa[0][kc], bv, o[0][n], 0, 0, 0);
                o[1][n] = __builtin_amdgcn_mfma_f32_16x16x32_bf16(pa[1][kc], bv, o[1][n], 0, 0, 0);
            }
    }

    // row-sums: reduce across quads (keys were quad-distributed)
#pragma unroll
    for (int h = 0; h < 2; h++) {
        rs[h] += __shfl_xor(rs[h], 16);
        rs[h] += __shfl_xor(rs[h], 32);
    }
    if (lane < 16) {
#pragma unroll
        for (int h = 0; h < 2; h++)
            lsum[(size_t)(split * 4 + b) * 4096 + qb * 128 + wave * 32 + h * 16 + lane] = rs[h];
    }

    // O partial -> bf16 opart via LDS transpose, two 64-q passes
    float* sO = reinterpret_cast<float*>(smem);   // [128 ch][68] f32 = 34816 B
#pragma unroll
    for (int half = 0; half < 2; half++) {
        __syncthreads();
        if ((wave >> 1) == half) {
#pragma unroll
            for (int h = 0; h < 2; h++)
#pragma unroll
                for (int n = 0; n < 8; n++)
#pragma unroll
                    for (int r = 0; r < 4; r++)
                        sO[(n * 16 + l16) * 68 + (wave & 1) * 32 + h * 16 + quad * 4 + r] =
                            o[h][n][r];
        }
        __syncthreads();
#pragma unroll
        for (int i = 0; i < 4; i++) {
            int u = i * 256 + t, c = u >> 3, g = u & 7;    // 128c x 8 groups of 8q
            f32x4 v0 = *(const f32x4*)(sO + c * 68 + g * 8);
            f32x4 v1 = *(const f32x4*)(sO + c * 68 + g * 8 + 4);
            unsigned int w[4];
            w[0] = pk_bf16(v0[0], v0[1]);
            w[1] = pk_bf16(v0[2], v0[3]);
            w[2] = pk_bf16(v1[0], v1[1]);
            w[3] = pk_bf16(v1[2], v1[3]);
            *(uint4*)(opart + ((size_t)(split * 4 + b) * 128 + c) * 4096 +
                      qb * 128 + half * 64 + g * 8) = make_uint4(w[0], w[1], w[2], w[3]);
        }
    }
}

// ---------------- K3: combine splits + mask blend ----------------------------------------
// grid (32 qb, 4 b) x 256: block = one 128-q tile.
__global__ void combine(const unsigned short* __restrict__ opart,
                        const float* __restrict__ lsum,
                        const float* __restrict__ x,
                        const float* __restrict__ mask,
                        float* __restrict__ out, int S) {
    const int qb = blockIdx.x, b = blockIdx.y, t = threadIdx.x;
    __shared__ float Linv[128];
    if (t < 128) {
        float L = 0.f;
        for (int s2 = 0; s2 < S; s2++)
            L += lsum[(size_t)(s2 * 4 + b) * 4096 + qb * 128 + t];
        Linv[t] = 1.f / fmaxf(L, 1e-37f);
    }
    __syncthreads();
#pragma unroll 4
    for (int i = 0; i < 16; i++) {
        int u = i * 256 + t, c = u >> 5, qg = u & 31, q0 = qg * 4;
        f32x4 acc = (f32x4){0.f, 0.f, 0.f, 0.f};
        for (int s2 = 0; s2 < S; s2++) {
            u16x4 pv = *(const u16x4*)(opart + ((size_t)(s2 * 4 + b) * 128 + c) * 4096 +
                                       qb * 128 + q0);
#pragma unroll
            for (int j = 0; j < 4; j++) acc[j] += bf2f(pv[j]);
        }
        f32x4 xv = *(const f32x4*)(x + ((size_t)b * 128 + c) * 4096 + qb * 128 + q0);
        f32x4 mv = *(const f32x4*)(mask + (size_t)b * 4096 + qb * 128 + q0);
        f32x4 res;
#pragma unroll
        for (int j = 0; j < 4; j++)
            res[j] = acc[j] * Linv[q0 + j] * (1.f - mv[j]) * (1.f / 9.f) + xv[j] * mv[j];
        *(f32x4*)(out + ((size_t)b * 128 + c) * 4096 + qb * 128 + q0) = res;
    }
}

extern "C" void kernel_launch(void* const* d_in, const int* in_sizes, int n_in,
                              void* d_out, int out_size, void* d_ws, size_t ws_size,
                              hipStream_t stream) {
    const float* x = (const float*)d_in[0];     // f32 (4,128,64,64)
    const float* mask = (const float*)d_in[1];  // f32 (4,1,64,64)
    float* out = (float*)d_out;                 // f32 (4,128,64,64)
    char* ws = (char*)d_ws;
    unsigned short* kmat = (unsigned short*)(ws);
    unsigned short* kT   = (unsigned short*)(ws + (size_t)4 * 1024 * 1024);
    unsigned short* xbT  = (unsigned short*)(ws + (size_t)8 * 1024 * 1024);
    float* lsum          = (float*)(ws + (size_t)12 * 1024 * 1024);
    unsigned short* opart = (unsigned short*)(ws + (size_t)13 * 1024 * 1024);

    // ws need: 13 MiB + S*4 MiB (opart bf16)
    int S, qbshift;
    if (ws_size >= (size_t)45 * 1024 * 1024)      { S = 8; qbshift = 5; }
    else if (ws_size >= (size_t)29 * 1024 * 1024) { S = 4; qbshift = 4; }
    else if (ws_size >= (size_t)21 * 1024 * 1024) { S = 2; qbshift = 3; }
    else return;

    prep<<<dim3(64, 4), 256, 0, stream>>>(x, kmat, kT, xbT);
    flash_attn<<<dim3(32 * 4 * S), 256, 0, stream>>>(kmat, kT, xbT, opart, lsum, S, qbshift);
    combine<<<dim3(32, 4), 256, 0, stream>>>(opart, lsum, x, mask, out, S);
}

// Round 10
// 152.514 us; speedup vs baseline: 2.9540x; 1.8759x over previous
//
#include <hip/hip_runtime.h>

// CAttention on MI355X (gfx950). Inputs f32, output f32.
// Q = box3(x)*log2(e), K = V = normalize(x+EPS), softmax over keys, per batch.
// Round 10: R6-verified skeleton (sK staged in LDS, S=4, f32 opart, 256B store chunks,
// launch_bounds(256,2), separate combine) + S^T trick from R9 (operand-swapped QK^T so
// P is born with q=lane: b64 sP writes, per-lane row-sum, butterfly only at end).
// Prep rebuilt: coalesced inv kernel (decouples cross-c norm) + c-split main (512 blocks).
// ws: kmat bf16 @0 | kT bf16 @4M | xbT bf16 @8M | lsum f32 @12M | inv f32 @12.25M | opart f32 @12.5M.

typedef short bf16x8 __attribute__((ext_vector_type(8)));
typedef float f32x4 __attribute__((ext_vector_type(4)));
typedef unsigned int u32x2 __attribute__((ext_vector_type(2)));

#define L2E 1.4426950408889634f

__device__ __forceinline__ unsigned short f2bf(float f) {
    unsigned int u;
    __builtin_memcpy(&u, &f, 4);
    u = u + 0x7FFFu + ((u >> 16) & 1u);   // RNE
    return (unsigned short)(u >> 16);
}
// pack two f32 -> bf16 pair (round to nearest, ties up)
__device__ __forceinline__ unsigned int pk_bf16(float a, float b) {
    unsigned int ua, ub;
    __builtin_memcpy(&ua, &a, 4);
    __builtin_memcpy(&ub, &b, 4);
    return ((ua + 0x8000u) >> 16) | ((ub + 0x8000u) & 0xFFFF0000u);
}

// ---------------- K0: inv[b][l] = rsqrt(sum_c (x+eps)^2) — fully coalesced ---------------
__global__ void prep_inv(const float* __restrict__ x, float* __restrict__ inv) {
    const int b = blockIdx.y, l = blockIdx.x * 256 + threadIdx.x;
    const float* xb = x + (size_t)b * 128 * 4096 + l;
    float sq = 0.f;
#pragma unroll 16
    for (int c = 0; c < 128; c++) {
        float v = xb[(size_t)c * 4096] + 1e-7f;
        sq += v * v;
    }
    inv[b * 4096 + l] = rsqrtf(sq);
}

// ---------------- K1: prep_main: kmat, kT, xbT for one (p-row, b, c-half) ----------------
// grid (64 p, 4 b, 2 z) x 256. All x loads are full-row 256B wave-coalesced.
__global__ void prep_main(const float* __restrict__ x,
                          const float* __restrict__ inv,
                          unsigned short* __restrict__ kmat,
                          unsigned short* __restrict__ kT,
                          unsigned short* __restrict__ xbT) {
    const int p = blockIdx.x, b = blockIdx.y, cb = blockIdx.z * 64;
    const int t = threadIdx.x, wave = t >> 6, lane = t & 63;

    __shared__ float sX[8][3][66];
    __shared__ float sMidT[64 * 68];      // [q][c-local], f32, stride 68 (272B, 16-mult)
    __shared__ __align__(16) unsigned short sQ[64 * 80];  // [q][c-local], stride 80 (160B)
    __shared__ float sInv[64];
    if (t < 64) sInv[t] = inv[b * 4096 + p * 64 + t];

    for (int c0 = 0; c0 < 64; c0 += 8) {
        __syncthreads();
#pragma unroll
        for (int i = 0; i < 6; i++) {                     // 24 coalesced row loads
            int pair = wave * 6 + i;
            int cc = pair / 3, r = pair - cc * 3;
            int pp = p + r - 1;
            float v = 0.f;
            if ((unsigned)pp < 64u)
                v = x[((size_t)b * 128 + cb + c0 + cc) * 4096 + pp * 64 + lane];
            sX[cc][r][1 + lane] = v;
        }
        if (t < 48) {                                     // zero q-borders
            int cc = t / 6, rr = (t % 6) >> 1, side = t & 1;
            sX[cc][rr][side * 65] = 0.f;
        }
        __syncthreads();
#pragma unroll
        for (int j = 0; j < 2; j++) {
            int cc = wave * 2 + j;
            float mid = sX[cc][1][1 + lane] + 1e-7f;
            sMidT[lane * 68 + c0 + cc] = mid;
            float sbox = 0.f;
#pragma unroll
            for (int r = 0; r < 3; r++)
                sbox += sX[cc][r][lane] + sX[cc][r][lane + 1] + sX[cc][r][lane + 2];
            sQ[lane * 80 + c0 + cc] = f2bf(sbox * L2E);
        }
    }
    __syncthreads();

    // xbT half-rows (64 q x 64 c): 512 items of 16B
#pragma unroll
    for (int i = 0; i < 2; i++) {
        int u = i * 256 + t, row = u >> 3, g = u & 7;
        *(bf16x8*)(xbT + ((size_t)b * 4096 + p * 64 + row) * 128 + cb + g * 8) =
            *(const bf16x8*)(sQ + row * 80 + g * 8);
    }
    // kmat half-rows: k = mid * inv
#pragma unroll
    for (int i = 0; i < 2; i++) {
        int u = i * 256 + t, q = u >> 3, g = u & 7;
        float iv = sInv[q];
        f32x4 a = *(const f32x4*)(sMidT + q * 68 + g * 8);
        f32x4 c = *(const f32x4*)(sMidT + q * 68 + g * 8 + 4);
        unsigned int w[4];
        w[0] = pk_bf16(a[0] * iv, a[1] * iv);
        w[1] = pk_bf16(a[2] * iv, a[3] * iv);
        w[2] = pk_bf16(c[0] * iv, c[1] * iv);
        w[3] = pk_bf16(c[2] * iv, c[3] * iv);
        *(uint4*)(kmat + ((size_t)b * 4096 + p * 64 + q) * 128 + cb + g * 8) =
            make_uint4(w[0], w[1], w[2], w[3]);
    }
    // kT rows [c][l]: 256 items = 64 c x 4 q-groups of 16
    {
        int c = t >> 2, qg = t & 3;
        unsigned int w[8];
#pragma unroll
        for (int j = 0; j < 8; j++) {
            int ql = qg * 16 + j * 2;
            w[j] = pk_bf16(sMidT[ql * 68 + c] * sInv[ql],
                           sMidT[(ql + 1) * 68 + c] * sInv[ql + 1]);
        }
        unsigned short* dst = kT + ((size_t)b * 128 + cb + c) * 4096 + p * 64 + qg * 16;
        *(uint4*)(dst) = make_uint4(w[0], w[1], w[2], w[3]);
        *(uint4*)(dst + 8) = make_uint4(w[4], w[5], w[6], w[7]);
    }
}

// ---------------- K2: split-K flash (R6 skeleton + S^T trick) ----------------------------
// grid 1D 32*4*S: combo = id & (4S-1) (b=combo&3, split=combo>>2) -> XCD-local; qb=id>>qbshift.
#define SK_STRIDE 136   // 272B rows
#define SV_STRIDE 72    // 144B rows
#define SP_STRIDE 72
#define SK_ELEMS (64 * SK_STRIDE)      // 8704
#define SV_ELEMS (128 * SV_STRIDE)     // 9216
#define SP_ELEMS (4 * 32 * SP_STRIDE)  // 9216

__global__ void __launch_bounds__(256, 2) flash_attn(
        const unsigned short* __restrict__ kmat,
        const unsigned short* __restrict__ kT,
        const unsigned short* __restrict__ xbT,
        float* __restrict__ opart,
        float* __restrict__ lsum,
        int nsplit, int qbshift) {
    const int combo = blockIdx.x & (4 * nsplit - 1);
    const int qb = blockIdx.x >> qbshift;        // 128-query tile, 0..31
    const int b = combo & 3, split = combo >> 2;
    const int nk = 4096 / nsplit, NIT = nk >> 6, kt_base = split * nk;
    const int t = threadIdx.x;
    const int wave = t >> 6, lane = t & 63;
    const int l16 = lane & 15, quad = lane >> 4;

    __shared__ __align__(16) unsigned short smem[SK_ELEMS + SV_ELEMS + SP_ELEMS]; // 54272 B
    unsigned short* sK = smem;                              // [64 keys][136]
    unsigned short* sV = smem + SK_ELEMS;                   // [128 ch][72]
    unsigned short* sP = smem + SK_ELEMS + SV_ELEMS + wave * 32 * SP_STRIDE;  // per-wave [32 q][72]

    // Q frags (B-operand of S^T): B[n=q=l16][k=c=quad*8+j] — same per-lane data as A-layout
    bf16x8 aq[2][4];
#pragma unroll
    for (int h = 0; h < 2; h++) {
        const unsigned short* xq =
            xbT + ((size_t)b * 4096 + qb * 128 + wave * 32 + h * 16 + l16) * 128 + quad * 8;
#pragma unroll
        for (int cc = 0; cc < 4; cc++) aq[h][cc] = *(const bf16x8*)(xq + cc * 32);
    }

    f32x4 o[2][8];
#pragma unroll
    for (int h = 0; h < 2; h++)
#pragma unroll
        for (int n = 0; n < 8; n++) o[h][n] = (f32x4){0.f, 0.f, 0.f, 0.f};
    float rs[2] = {0.f, 0.f};

    const unsigned short* kmb = kmat + (size_t)b * 4096 * 128;
    const unsigned short* ktb = kT + (size_t)b * 128 * 4096;

    bf16x8 kreg[4], vreg[4];
#pragma unroll
    for (int i = 0; i < 4; i++) {
        int e = i * 2048 + t * 8;
        kreg[i] = *(const bf16x8*)(kmb + (size_t)(kt_base + (e >> 7)) * 128 + (e & 127));
        vreg[i] = *(const bf16x8*)(ktb + (size_t)(e >> 6) * 4096 + kt_base + (e & 63));
    }

    for (int it = 0; it < NIT; it++) {
        __syncthreads();                          // prior iter's LDS reads done
#pragma unroll
        for (int i = 0; i < 4; i++) {
            int e = i * 2048 + t * 8;
            *(bf16x8*)(sK + (e >> 7) * SK_STRIDE + (e & 127)) = kreg[i];
            *(bf16x8*)(sV + (e >> 6) * SV_STRIDE + (e & 63)) = vreg[i];
        }
        __syncthreads();                          // tiles visible
        if (it + 1 < NIT) {
            int kt0 = kt_base + (it + 1) * 64;
#pragma unroll
            for (int i = 0; i < 4; i++) {
                int e = i * 2048 + t * 8;
                kreg[i] = *(const bf16x8*)(kmb + (size_t)(kt0 + (e >> 7)) * 128 + (e & 127));
                vreg[i] = *(const bf16x8*)(ktb + (size_t)(e >> 6) * 4096 + kt0 + (e & 63));
            }
        }

        // S^T = K Q^T: A = sK frag (m=key), B = aq (n=q).
        // D: lane holds S^T[key = k4*16 + quad*4 + r][q = l16].
        f32x4 s[2][4];
#pragma unroll
        for (int h = 0; h < 2; h++)
#pragma unroll
            for (int k4 = 0; k4 < 4; k4++) s[h][k4] = (f32x4){0.f, 0.f, 0.f, 0.f};
#pragma unroll
        for (int cc = 0; cc < 4; cc++) {
#pragma unroll
            for (int k4 = 0; k4 < 4; k4++) {
                bf16x8 ak = *(const bf16x8*)(sK + (k4 * 16 + l16) * SK_STRIDE + cc * 32 + quad * 8);
                s[0][k4] = __builtin_amdgcn_mfma_f32_16x16x32_bf16(ak, aq[0][cc], s[0][k4], 0, 0, 0);
                s[1][k4] = __builtin_amdgcn_mfma_f32_16x16x32_bf16(ak, aq[1][cc], s[1][k4], 0, 0, 0);
            }
        }

        // p = 2^s; lane-local row-sum (q fixed = l16); b64-pack consecutive keys -> sP
#pragma unroll
        for (int h = 0; h < 2; h++) {
#pragma unroll
            for (int k4 = 0; k4 < 4; k4++) {
                float p0 = exp2f(s[h][k4][0]), p1 = exp2f(s[h][k4][1]);
                float p2 = exp2f(s[h][k4][2]), p3 = exp2f(s[h][k4][3]);
                rs[h] += (p0 + p1) + (p2 + p3);
                u32x2 d;
                d[0] = pk_bf16(p0, p1);
                d[1] = pk_bf16(p2, p3);
                // P[q=l16][key = k4*16 + quad*4 + 0..3]
                *(u32x2*)(sP + (h * 16 + l16) * SP_STRIDE + k4 * 16 + quad * 4) = d;
            }
        }
        asm volatile("" ::: "memory");   // DS in-order per wave; stop compiler reorder
        bf16x8 pa[2][2];
#pragma unroll
        for (int h = 0; h < 2; h++)
#pragma unroll
            for (int kc = 0; kc < 2; kc++)
                pa[h][kc] = *(const bf16x8*)(sP + (h * 16 + l16) * SP_STRIDE + kc * 32 + quad * 8);
        asm volatile("" ::: "memory");

        // O += P V : A = pa (m=q), B = sV frag (n=c)
#pragma unroll
        for (int kc = 0; kc < 2; kc++)
#pragma unroll
            for (int n = 0; n < 8; n++) {
                bf16x8 bv = *(const bf16x8*)(sV + (n * 16 + l16) * SV_STRIDE + kc * 32 + quad * 8);
                o[0][n] = __builtin_amdgcn_mfma_f32_16x16x32_bf16(pa[0][kc], bv, o[0][n], 0, 0, 0);
                o[1][n] = __builtin_amdgcn_mfma_f32_16x16x32_bf16(pa[1][kc], bv, o[1][n], 0, 0, 0);
            }
    }

    // row-sums: keys were quad-distributed -> reduce across quads once
#pragma unroll
    for (int h = 0; h < 2; h++) {
        rs[h] += __shfl_xor(rs[h], 16);
        rs[h] += __shfl_xor(rs[h], 32);
    }
    if (lane < 16) {
#pragma unroll
        for (int h = 0; h < 2; h++)
            lsum[(size_t)(split * 4 + b) * 4096 + qb * 128 + wave * 32 + h * 16 + lane] = rs[h];
    }

    // O partial (f32, 256B chunks — R6-verified clean write path), two 64-q passes
    float* sO = reinterpret_cast<float*>(smem);   // [128 ch][68] f32 = 34816 B
#pragma unroll
    for (int half = 0; half < 2; half++) {
        __syncthreads();
        if ((wave >> 1) == half) {
#pragma unroll
            for (int h = 0; h < 2; h++)
#pragma unroll
                for (int n = 0; n < 8; n++)
#pragma unroll
                    for (int r = 0; r < 4; r++)
                        sO[(n * 16 + l16) * 68 + (wave & 1) * 32 + h * 16 + quad * 4 + r] =
                            o[h][n][r];
        }
        __syncthreads();
#pragma unroll
        for (int i = 0; i < 8; i++) {
            int c = (t >> 4) + i * 16, qj = (t & 15) * 4;
            *(f32x4*)(opart + ((size_t)(split * 4 + b) * 128 + c) * 4096 +
                      qb * 128 + half * 64 + qj) = *(const f32x4*)(sO + c * 68 + qj);
        }
    }
}

// ---------------- K3: combine splits + mask blend ----------------------------------------
// grid (64 qb64, 4 b) x 256.
__global__ void combine(const float* __restrict__ opart,
                        const float* __restrict__ lsum,
                        const float* __restrict__ x,
                        const float* __restrict__ mask,
                        float* __restrict__ out, int S) {
    const int qb = blockIdx.x, b = blockIdx.y, t = threadIdx.x;
    __shared__ float Linv[64];
    if (t < 64) {
        float L = 0.f;
        for (int s2 = 0; s2 < S; s2++)
            L += lsum[(size_t)(s2 * 4 + b) * 4096 + qb * 64 + t];
        Linv[t] = 1.f / fmaxf(L, 1e-37f);
    }
    __syncthreads();
#pragma unroll
    for (int i = 0; i < 8; i++) {
        int c = (t >> 4) + i * 16, qj = (t & 15) * 4;
        size_t qoff = (size_t)qb * 64 + qj;
        f32x4 acc = (f32x4){0.f, 0.f, 0.f, 0.f};
        for (int s2 = 0; s2 < S; s2++) {
            f32x4 p = *(const f32x4*)(opart + ((size_t)(s2 * 4 + b) * 128 + c) * 4096 + qoff);
#pragma unroll
            for (int j = 0; j < 4; j++) acc[j] += p[j];
        }
        f32x4 xv = *(const f32x4*)(x + ((size_t)b * 128 + c) * 4096 + qoff);
        f32x4 mv = *(const f32x4*)(mask + (size_t)b * 4096 + qoff);
        f32x4 res;
#pragma unroll
        for (int j = 0; j < 4; j++)
            res[j] = acc[j] * Linv[qj + j] * (1.f - mv[j]) * (1.f / 9.f) + xv[j] * mv[j];
        *(f32x4*)(out + ((size_t)b * 128 + c) * 4096 + qoff) = res;
    }
}

extern "C" void kernel_launch(void* const* d_in, const int* in_sizes, int n_in,
                              void* d_out, int out_size, void* d_ws, size_t ws_size,
                              hipStream_t stream) {
    const float* x = (const float*)d_in[0];     // f32 (4,128,64,64)
    const float* mask = (const float*)d_in[1];  // f32 (4,1,64,64)
    float* out = (float*)d_out;                 // f32 (4,128,64,64)
    char* ws = (char*)d_ws;
    unsigned short* kmat = (unsigned short*)(ws);
    unsigned short* kT   = (unsigned short*)(ws + (size_t)4 * 1024 * 1024);
    unsigned short* xbT  = (unsigned short*)(ws + (size_t)8 * 1024 * 1024);
    float* lsum          = (float*)(ws + (size_t)12 * 1024 * 1024);
    float* inv           = (float*)(ws + (size_t)12 * 1024 * 1024 + 256 * 1024);
    float* opart         = (float*)(ws + (size_t)12 * 1024 * 1024 + 512 * 1024);

    // ws need: 12.5 MiB + S*8 MiB (opart f32)
    int S, qbshift;
    if (ws_size >= (size_t)46137344)      { S = 4; qbshift = 4; }   // 44 MiB
    else if (ws_size >= (size_t)29360128) { S = 2; qbshift = 3; }   // 28 MiB
    else if (ws_size >= (size_t)22020096) { S = 1; qbshift = 2; }   // 21 MiB
    else return;

    prep_inv<<<dim3(16, 4), 256, 0, stream>>>(x, inv);
    prep_main<<<dim3(64, 4, 2), 256, 0, stream>>>(x, inv, kmat, kT, xbT);
    flash_attn<<<dim3(32 * 4 * S), 256, 0, stream>>>(kmat, kT, xbT, opart, lsum, S, qbshift);
    combine<<<dim3(64, 4), 256, 0, stream>>>(opart, lsum, x, mask, out, S);
}